// Round 2
// baseline (579.733 us; speedup 1.0000x reference)
//
#include <hip/hip_runtime.h>

// 3x3 PCF soft-shadow, tile-binned for L2 locality.
// vis[i] = (1/9) * sum_{ii,jj} sigmoid((zbuf[b, clip(y+ii), clip(x+jj)] - (depth_z[i]-BIAS)) * 1000)

#define SHARPNESS 1000.0f
#define BIAS 0.008f

// ---------------- specialized path: N=8, S=2048, HWK=1048576 ----------------
#define S_IMG   2048
#define NBATCH  8
#define HWK     1048576
#define TSHIFT  8          // tile height 256 rows -> 2 MiB per tile per batch
#define NT      8
#define PXB     8192       // pixels per block (256 thr * 32)
#define PBT     32

__device__ __forceinline__ float sig9(float bb, float a) {
    // sigmoid((bb-a)*1000) = 1/(1+exp((a-bb)*1000))
    return 1.0f / (1.0f + __expf((a - bb) * SHARPNESS));
}

__global__ __launch_bounds__(256, 4) void pcf_binned(
    const float* __restrict__ zbuf,     // [8, 2048, 2048]
    const float* __restrict__ depth,    // [8, 1048576]
    const int2*  __restrict__ xy,       // [8, 1048576] (x,y)
    float*       __restrict__ out)      // [8, 1048576]
{
    __shared__ unsigned int keys[PXB];          // 32 KiB
    __shared__ unsigned int cnt[NT];
    __shared__ unsigned int cursor[NT];
    __shared__ unsigned int start[NT + 1];

    const int tid   = threadIdx.x;
    const int batch = blockIdx.x & (NBATCH - 1);   // consecutive blocks -> different XCDs
    const int bib   = blockIdx.x >> 3;             // block index within batch
    const size_t pixBase = (size_t)batch * HWK + (size_t)bib * PXB;
    const float* zb = zbuf + (size_t)batch * ((size_t)S_IMG * S_IMG);

    const unsigned long long lmask_lt = (1ull << (tid & 63)) - 1ull;

    if (tid < NT) cnt[tid] = 0;
    __syncthreads();

    // ---- Phase A1: histogram pixels by y-tile (wave-aggregated LDS atomics)
    for (int j = 0; j < PBT; ++j) {
        const int idx = j * 256 + tid;
        const int2 p  = xy[pixBase + idx];
        const int tile = p.y >> TSHIFT;
#pragma unroll
        for (int t = 0; t < NT; ++t) {
            const unsigned long long m = __ballot(tile == t);
            if (tile == t && (m & lmask_lt) == 0ull)       // leader lane
                atomicAdd(&cnt[t], (unsigned)__popcll(m));
        }
    }
    __syncthreads();

    if (tid == 0) {
        unsigned run = 0;
#pragma unroll
        for (int t = 0; t < NT; ++t) { start[t] = run; cursor[t] = run; run += cnt[t]; }
        start[NT] = run;   // == PXB
    }
    __syncthreads();

    // ---- Phase A2: scatter packed keys into tile-contiguous LDS bins
    for (int j = 0; j < PBT; ++j) {
        const int idx = j * 256 + tid;
        const int2 p  = xy[pixBase + idx];
        const int tile = p.y >> TSHIFT;
        const unsigned key = ((unsigned)p.x << 21) |
                             ((unsigned)(p.y & ((1 << TSHIFT) - 1)) << 13) |
                             (unsigned)idx;
        unsigned pos = 0;
#pragma unroll
        for (int t = 0; t < NT; ++t) {
            const unsigned long long m = __ballot(tile == t);
            if (tile == t) {
                const int rank   = (int)__popcll(m & lmask_lt);
                const int leader = (int)__ffsll((unsigned long long)m) - 1;
                unsigned base;
                if (rank == 0) base = atomicAdd(&cursor[t], (unsigned)__popcll(m));
                base = (unsigned)__shfl((int)base, leader);
                pos = base + (unsigned)rank;
            }
        }
        keys[pos] = key;
    }
    __syncthreads();

    // ---- Process tiles in order: all resident blocks march in phase,
    //      so each XCD's L2 holds ~one 2 MiB tile of its own batch.
    for (int t = 0; t < NT; ++t) {
        const int s = (int)start[t];
        const int e = (int)start[t + 1];
        for (int k = s + tid; k < e; k += 256) {
            const unsigned key = keys[k];
            const int x    = (int)(key >> 21);
            const int ylow = (int)((key >> 13) & ((1 << TSHIFT) - 1));
            const int idx  = (int)(key & (PXB - 1));
            const int y    = (t << TSHIFT) | ylow;

            const float a = depth[pixBase + idx] - BIAS;

            const int xm = max(x - 1, 0), xp = min(x + 1, S_IMG - 1);
            const int ym = max(y - 1, 0), yp = min(y + 1, S_IMG - 1);
            const float* r0 = zb + (size_t)ym * S_IMG;
            const float* r1 = zb + (size_t)y  * S_IMG;
            const float* r2 = zb + (size_t)yp * S_IMG;

            const float t00 = r0[xm], t01 = r0[x], t02 = r0[xp];
            const float t10 = r1[xm], t11 = r1[x], t12 = r1[xp];
            const float t20 = r2[xm], t21 = r2[x], t22 = r2[xp];

            float vis = 0.0f;
            vis += sig9(t00, a); vis += sig9(t01, a); vis += sig9(t02, a);
            vis += sig9(t10, a); vis += sig9(t11, a); vis += sig9(t12, a);
            vis += sig9(t20, a); vis += sig9(t21, a); vis += sig9(t22, a);

            out[pixBase + idx] = vis * (1.0f / 9.0f);
        }
    }
}

// ---------------- generic fallback (round-1 kernel) ----------------
__global__ __launch_bounds__(256) void pcf_shadow_generic(
    const float* __restrict__ zbuf,
    const float* __restrict__ depth_z,
    const int2*  __restrict__ xy,
    const int*   __restrict__ image_size_p,
    float*       __restrict__ out,
    int total, int zbuf_elems)
{
    const int i = blockIdx.x * blockDim.x + threadIdx.x;
    if (i >= total) return;

    const int S  = *image_size_p;
    const int SS = S * S;
    const int N  = zbuf_elems / SS;
    const int hwk = total / N;
    const int b   = i / hwk;

    const float a = depth_z[i] - BIAS;
    const int2 p  = xy[i];
    const float* base = zbuf + (size_t)b * (size_t)SS;

    float vis = 0.0f;
#pragma unroll
    for (int ii = -1; ii <= 1; ++ii) {
        const int yi = min(max(p.y + ii, 0), S - 1);
        const float* row = base + (size_t)yi * (size_t)S;
#pragma unroll
        for (int jj = -1; jj <= 1; ++jj) {
            const int xi = min(max(p.x + jj, 0), S - 1);
            vis += 1.0f / (1.0f + __expf((a - row[xi]) * SHARPNESS));
        }
    }
    out[i] = vis * (1.0f / 9.0f);
}

extern "C" void kernel_launch(void* const* d_in, const int* in_sizes, int n_in,
                              void* d_out, int out_size, void* d_ws, size_t ws_size,
                              hipStream_t stream) {
    const float* zbuf     = (const float*)d_in[0];
    const float* depth_z  = (const float*)d_in[1];
    const int2*  xy       = (const int2*)d_in[2];
    const int*   img_size = (const int*)d_in[3];
    float*       out      = (float*)d_out;

    const int zbuf_elems = in_sizes[0];   // N*S*S
    const int total      = in_sizes[1];   // N*H*W*K

    if (zbuf_elems == NBATCH * S_IMG * S_IMG && total == NBATCH * HWK) {
        const int grid = (NBATCH * HWK) / PXB;   // 1024 blocks, all resident
        pcf_binned<<<grid, 256, 0, stream>>>(zbuf, depth_z, xy, out);
    } else {
        const int block = 256;
        const int grid  = (total + block - 1) / block;
        pcf_shadow_generic<<<grid, block, 0, stream>>>(zbuf, depth_z, xy, img_size,
                                                       out, total, zbuf_elems);
    }
}

// Round 4
// 568.605 us; speedup vs baseline: 1.0196x; 1.0196x over previous
//
#include <hip/hip_runtime.h>

// 3x3 PCF soft-shadow.
// vis[i] = (1/9) * sum_{ii,jj} sigmoid((zbuf[b, clip(y+ii), clip(x+jj)] - (depth_z[i]-BIAS)) * 1000)
//
// R4: one unaligned dwordx4 per zbuf row (3 VMEM gathers/pixel instead of 9),
// XCD-batch affinity swizzle, nontemporal stream accesses.

#define SHARPNESS 1000.0f
#define BIAS 0.008f

#define S_IMG   2048
#define NBATCH  8
#define HWK     (1 << 20)

// float4 with 4-byte alignment so the backend may emit a dword-aligned
// global_load_dwordx4 (gfx9+ allows misaligned multi-dword).
typedef float f4u __attribute__((ext_vector_type(4), aligned(4)));
typedef int   i2v __attribute__((ext_vector_type(2)));

__device__ __forceinline__ float sigf(float bb, float a) {
    // sigmoid((bb-a)*1000) = 1/(1+exp((a-bb)*1000)); saturates correctly.
    return 1.0f / (1.0f + __expf((a - bb) * SHARPNESS));
}

__device__ __forceinline__ float selv(f4u v, int s) {
    return (s == 0) ? v.x : (s == 1) ? v.y : (s == 2) ? v.z : v.w;
}

__global__ __launch_bounds__(256) void pcf_fast(
    const float* __restrict__ zbuf,     // [8, 2048, 2048]
    const float* __restrict__ depth,    // [8, HWK]
    const i2v*   __restrict__ xy,       // [8, HWK] (x,y)
    float*       __restrict__ out)      // [8, HWK]
{
    // XCD affinity: consecutive blocks round-robin across XCDs, so batch =
    // blockIdx & 7 pins each XCD's gathers to one 16 MiB zbuf image.
    const int batch = blockIdx.x & (NBATCH - 1);
    const int bib   = blockIdx.x >> 3;
    const size_t i  = (size_t)batch * HWK + (size_t)bib * 256 + threadIdx.x;

    const float a = __builtin_nontemporal_load(&depth[i]) - BIAS;
    const i2v p   = __builtin_nontemporal_load(&xy[i]);
    const int x = p.x, y = p.y;

    const float* zb = zbuf + (size_t)batch * ((size_t)S_IMG * S_IMG);
    const int ym = max(y - 1, 0), yp = min(y + 1, S_IMG - 1);
    const float* r0 = zb + (size_t)ym * S_IMG;
    const float* r1 = zb + (size_t)y  * S_IMG;
    const float* r2 = zb + (size_t)yp * S_IMG;

    float vis;
    if (x >= 1 && x <= S_IMG - 3) {
        // Interior: window [x-1 .. x+2], taps are .x/.y/.z
        const int xb = x - 1;
        const f4u v0 = *(const f4u*)(r0 + xb);
        const f4u v1 = *(const f4u*)(r1 + xb);
        const f4u v2 = *(const f4u*)(r2 + xb);
        vis = sigf(v0.x, a) + sigf(v0.y, a) + sigf(v0.z, a)
            + sigf(v1.x, a) + sigf(v1.y, a) + sigf(v1.z, a)
            + sigf(v2.x, a) + sigf(v2.y, a) + sigf(v2.z, a);
    } else {
        // Edge columns: clamped window + per-tap select. Base never exceeds
        // S-4 so the 16B read stays inside the row.
        const int xb = min(max(x - 1, 0), S_IMG - 4);
        const int s0 = max(x - 1, 0) - xb;
        const int s1 = x - xb;
        const int s2 = min(x + 1, S_IMG - 1) - xb;
        const f4u v0 = *(const f4u*)(r0 + xb);
        const f4u v1 = *(const f4u*)(r1 + xb);
        const f4u v2 = *(const f4u*)(r2 + xb);
        vis = sigf(selv(v0, s0), a) + sigf(selv(v0, s1), a) + sigf(selv(v0, s2), a)
            + sigf(selv(v1, s0), a) + sigf(selv(v1, s1), a) + sigf(selv(v1, s2), a)
            + sigf(selv(v2, s0), a) + sigf(selv(v2, s1), a) + sigf(selv(v2, s2), a);
    }
    __builtin_nontemporal_store(vis * (1.0f / 9.0f), &out[i]);
}

// ---------------- generic fallback ----------------
__global__ __launch_bounds__(256) void pcf_shadow_generic(
    const float* __restrict__ zbuf,
    const float* __restrict__ depth_z,
    const int2*  __restrict__ xy,
    const int*   __restrict__ image_size_p,
    float*       __restrict__ out,
    int total, int zbuf_elems)
{
    const int i = blockIdx.x * blockDim.x + threadIdx.x;
    if (i >= total) return;

    const int S  = *image_size_p;
    const int SS = S * S;
    const int N  = zbuf_elems / SS;
    const int hwk = total / N;
    const int b   = i / hwk;

    const float a = depth_z[i] - BIAS;
    const int2 p  = xy[i];
    const float* base = zbuf + (size_t)b * (size_t)SS;

    float vis = 0.0f;
#pragma unroll
    for (int ii = -1; ii <= 1; ++ii) {
        const int yi = min(max(p.y + ii, 0), S - 1);
        const float* row = base + (size_t)yi * (size_t)S;
#pragma unroll
        for (int jj = -1; jj <= 1; ++jj) {
            const int xi = min(max(p.x + jj, 0), S - 1);
            vis += 1.0f / (1.0f + __expf((a - row[xi]) * SHARPNESS));
        }
    }
    out[i] = vis * (1.0f / 9.0f);
}

extern "C" void kernel_launch(void* const* d_in, const int* in_sizes, int n_in,
                              void* d_out, int out_size, void* d_ws, size_t ws_size,
                              hipStream_t stream) {
    const float* zbuf     = (const float*)d_in[0];
    const float* depth_z  = (const float*)d_in[1];
    const int*   xy_raw   = (const int*)d_in[2];
    const int*   img_size = (const int*)d_in[3];
    float*       out      = (float*)d_out;

    const int zbuf_elems = in_sizes[0];   // N*S*S
    const int total      = in_sizes[1];   // N*H*W*K

    if (zbuf_elems == NBATCH * S_IMG * S_IMG && total == NBATCH * HWK) {
        const int grid = (NBATCH * HWK) / 256;   // 32768 blocks
        pcf_fast<<<grid, 256, 0, stream>>>(zbuf, depth_z, (const i2v*)xy_raw, out);
    } else {
        const int block = 256;
        const int grid  = (total + block - 1) / block;
        pcf_shadow_generic<<<grid, block, 0, stream>>>(zbuf, depth_z, (const int2*)xy_raw,
                                                       img_size, out, total, zbuf_elems);
    }
}